// Round 12
// baseline (106.926 us; speedup 1.0000x reference)
//
#include <hip/hip_runtime.h>

#define H 512
#define W 512
#define HW (H * W)
#define T 128
#define DECAY 0.8f

typedef float v4f __attribute__((ext_vector_type(4)));
typedef unsigned int v2u __attribute__((ext_vector_type(2)));
typedef _Float16 h2 __attribute__((ext_vector_type(2)));
typedef __fp16 hr2 __attribute__((ext_vector_type(2)));   // cvt_pkrtz native type

__device__ __forceinline__ float dot2(unsigned int a, unsigned int b, float c) {
    return __builtin_amdgcn_fdot2(__builtin_bit_cast(h2, a),
                                  __builtin_bit_cast(h2, b), c, false);
}

// ---------------------------------------------------------------------------
// Pass A: pointwise double-EMA scan (~33 us, ~6.1 TB/s). Block 0 also packs
// the conv weights into f16 pairs.
// ---------------------------------------------------------------------------
__global__ __launch_bounds__(256) void scan_chunk(
    const float* __restrict__ x, unsigned int* __restrict__ Rbuf,
    float* __restrict__ state, const float* __restrict__ wp,
    unsigned int* __restrict__ wq, int t0, int tc)
{
    if (t0 == 0 && blockIdx.x == 0 && threadIdx.x < 9) {
        int ky = threadIdx.x;
        unsigned int hh[9];
        #pragma unroll
        for (int kx = 0; kx < 9; ++kx) {
            _Float16 hv = (_Float16)wp[ky * 9 + kx];
            hh[kx] = (unsigned int)__builtin_bit_cast(unsigned short, hv);
        }
        wq[ky * 6 + 0] = hh[0] | (hh[1] << 16);
        wq[ky * 6 + 1] = hh[2] | (hh[3] << 16);
        wq[ky * 6 + 2] = hh[4] | (hh[5] << 16);
        wq[ky * 6 + 3] = hh[6] | (hh[7] << 16);
        wq[ky * 6 + 4] = hh[8];
        wq[ky * 6 + 5] = hh[8] << 16;
    }

    const int gid = blockIdx.x * 256 + threadIdx.x;      // 0 .. HW/4-1
    const v4f* xp = (const v4f*)x + (size_t)t0 * (HW / 4) + gid;
    v2u* rp = (v2u*)Rbuf + gid;
    v4f* st = (v4f*)state;

    v4f p, r;
    if (t0 == 0) {
        p = (v4f)0.f; r = (v4f)0.f;
    } else {
        p = st[gid];
        r = st[HW / 4 + gid];
    }

#define SCAN_STEP(xv)                                                        \
    {                                                                        \
        hr2 h0 = __builtin_amdgcn_cvt_pkrtz(r.x, r.y);                       \
        hr2 h1 = __builtin_amdgcn_cvt_pkrtz(r.z, r.w);                       \
        v2u pk;                                                              \
        pk.x = __builtin_bit_cast(unsigned int, h0);                         \
        pk.y = __builtin_bit_cast(unsigned int, h1);                         \
        rp[(size_t)t * (HW / 4)] = pk;                                       \
        v4f rn = DECAY * r + p;                                              \
        p = DECAY * p + (xv);                                                \
        r = rn;                                                              \
        ++t;                                                                 \
    }

    int t = 0;
    const int t4 = tc & ~3;
    for (; t < t4;) {
        v4f x0 = __builtin_nontemporal_load(&xp[(size_t)(t + 0) * (HW / 4)]);
        v4f x1 = __builtin_nontemporal_load(&xp[(size_t)(t + 1) * (HW / 4)]);
        v4f x2 = __builtin_nontemporal_load(&xp[(size_t)(t + 2) * (HW / 4)]);
        v4f x3 = __builtin_nontemporal_load(&xp[(size_t)(t + 3) * (HW / 4)]);
        SCAN_STEP(x0); SCAN_STEP(x1); SCAN_STEP(x2); SCAN_STEP(x3);
    }
    for (; t < tc;) {
        v4f xv = __builtin_nontemporal_load(&xp[(size_t)t * (HW / 4)]);
        SCAN_STEP(xv);
    }
#undef SCAN_STEP

    st[gid] = p;
    st[HW / 4 + gid] = r;
}

// ---------------------------------------------------------------------------
// Pass B: 9x9 conv, f16 in / fp32 out, v_dot2_f32_f16 — NO LDS, no barriers.
// Thread = 4-wide x 8-tall patch; loads its 16 window rows (3 x b64) straight
// from global. Wave chunk-0 loads are 64x8B contiguous (coalesced); shifted
// chunks hit the same lines in L1/L2 (halo reuse is cache-resident; guide
// lesson: don't LDS-stage what the caches fit). Latency hidden by TLP.
// Tile 256x32, one time plane per block.
// ---------------------------------------------------------------------------
#define BX 256
#define BY 32

__global__ __launch_bounds__(256) void conv_direct(
    const unsigned short* __restrict__ Rbuf, const unsigned int* __restrict__ wq,
    float* __restrict__ out, int t0)
{
    const int tid = threadIdx.x;
    const int tX = blockIdx.x, tY = blockIdx.y, tz = blockIdx.z;
    const unsigned short* Rp = Rbuf + (size_t)tz * HW;

    unsigned int wk[54];               // uniform -> SGPRs
    #pragma unroll
    for (int q = 0; q < 54; ++q) wk[q] = wq[q];

    const int i = tid & 63;            // col chunk: 4 output cols at 4i
    const int j = tid >> 6;            // 0..3 -> output rows 8j..8j+7
    const int gx0 = tX * BX - 4 + 4 * i;   // window col base (chunk 0)
    const int gyb = tY * BY - 4 + 8 * j;   // first window row

    const bool c0 = (unsigned)gx0 <= (unsigned)(W - 4);
    const bool c1 = (unsigned)(gx0 + 4) <= (unsigned)(W - 4);
    const bool c2 = (unsigned)(gx0 + 8) <= (unsigned)(W - 4);

    float acc[8][4];
    #pragma unroll
    for (int a = 0; a < 8; ++a)
        #pragma unroll
        for (int b = 0; b < 4; ++b) acc[a][b] = 0.f;

    #pragma unroll
    for (int r = 0; r < 16; ++r) {
        const int gy = gyb + r;
        const bool rok = (unsigned)gy < (unsigned)H;
        const unsigned short* rowp = Rp + (size_t)gy * W;
        uint2 va = (rok && c0) ? *(const uint2*)(rowp + gx0)     : make_uint2(0u, 0u);
        uint2 vb = (rok && c1) ? *(const uint2*)(rowp + gx0 + 4) : make_uint2(0u, 0u);
        uint2 vc = (rok && c2) ? *(const uint2*)(rowp + gx0 + 8) : make_uint2(0u, 0u);
        unsigned int e0 = va.x, e1 = va.y, e2 = vb.x;
        unsigned int e3 = vb.y, e4 = vc.x, e5 = vc.y;
        unsigned int o0 = __builtin_amdgcn_alignbit(e1, e0, 16);
        unsigned int o1 = __builtin_amdgcn_alignbit(e2, e1, 16);
        unsigned int o2 = __builtin_amdgcn_alignbit(e3, e2, 16);
        unsigned int o3 = __builtin_amdgcn_alignbit(e4, e3, 16);
        unsigned int o4 = __builtin_amdgcn_alignbit(e5, e4, 16);
        #pragma unroll
        for (int oy = 0; oy < 8; ++oy) {
            const int ky = r - oy;                 // compile-time after unroll
            if (ky >= 0 && ky <= 8) {
                const unsigned int* wc = &wk[ky * 6];
                acc[oy][0] = dot2(e0, wc[0], acc[oy][0]);
                acc[oy][0] = dot2(e1, wc[1], acc[oy][0]);
                acc[oy][0] = dot2(e2, wc[2], acc[oy][0]);
                acc[oy][0] = dot2(e3, wc[3], acc[oy][0]);
                acc[oy][0] = dot2(e4, wc[4], acc[oy][0]);
                acc[oy][1] = dot2(o0, wc[0], acc[oy][1]);
                acc[oy][1] = dot2(o1, wc[1], acc[oy][1]);
                acc[oy][1] = dot2(o2, wc[2], acc[oy][1]);
                acc[oy][1] = dot2(o3, wc[3], acc[oy][1]);
                acc[oy][1] = dot2(o4, wc[4], acc[oy][1]);
                acc[oy][2] = dot2(e1, wc[0], acc[oy][2]);
                acc[oy][2] = dot2(e2, wc[1], acc[oy][2]);
                acc[oy][2] = dot2(e3, wc[2], acc[oy][2]);
                acc[oy][2] = dot2(e4, wc[3], acc[oy][2]);
                acc[oy][2] = dot2(e5, wc[4], acc[oy][2]);
                acc[oy][3] = dot2(o1, wc[0], acc[oy][3]);
                acc[oy][3] = dot2(o2, wc[1], acc[oy][3]);
                acc[oy][3] = dot2(o3, wc[2], acc[oy][3]);
                acc[oy][3] = dot2(o4, wc[3], acc[oy][3]);
                acc[oy][3] = dot2(e5, wc[5], acc[oy][3]);
            }
        }
    }

    float* op = out + (size_t)(t0 + tz) * HW
                    + (size_t)((tY * BY + 8 * j) * W) + (tX * BX + 4 * i);
    #pragma unroll
    for (int oy = 0; oy < 8; ++oy) {
        v4f v = {acc[oy][0], acc[oy][1], acc[oy][2], acc[oy][3]};
        __builtin_nontemporal_store(v, (v4f*)(op + (size_t)oy * W));
    }
}

// ---------------------------------------------------------------------------
extern "C" void kernel_launch(void* const* d_in, const int* in_sizes, int n_in,
                              void* d_out, int out_size, void* d_ws, size_t ws_size,
                              hipStream_t stream) {
    const float* x = (const float*)d_in[0];  // [128,1,512,512]
    const float* w = (const float*)d_in[1];  // [1,1,9,9]
    float* out = (float*)d_out;              // [128,1,512,512]

    unsigned int* wq = (unsigned int*)d_ws;                    // 64 u32 slot
    float* state = (float*)((char*)d_ws + 256);                // 2 fp32 planes
    unsigned short* Rbuf = (unsigned short*)(state + 2 * (size_t)HW);

    size_t head_b = 256 + 2 * (size_t)HW * sizeof(float);
    size_t plane_b = (size_t)HW * sizeof(unsigned short);
    int maxTc = 1;
    if (ws_size > head_b + plane_b)
        maxTc = (int)((ws_size - head_b) / plane_b);
    int Tc = T;
    if (Tc > maxTc) Tc = maxTc;
    if (Tc < 1) Tc = 1;

    for (int t0 = 0; t0 < T; t0 += Tc) {
        int tc = T - t0;
        if (tc > Tc) tc = Tc;
        scan_chunk<<<dim3(HW / 1024), 256, 0, stream>>>(
            x, (unsigned int*)Rbuf, state, w, wq, t0, tc);
        conv_direct<<<dim3(W / BX, H / BY, tc), 256, 0, stream>>>(
            Rbuf, wq, out, t0);
    }
}

// Round 13
// 95.674 us; speedup vs baseline: 1.1176x; 1.1176x over previous
//
#include <hip/hip_runtime.h>

#define H 512
#define W 512
#define HW (H * W)
#define T 128
#define DECAY 0.8f

typedef float v4f __attribute__((ext_vector_type(4)));
typedef unsigned int v2u __attribute__((ext_vector_type(2)));
typedef _Float16 h2 __attribute__((ext_vector_type(2)));
typedef __fp16 hr2 __attribute__((ext_vector_type(2)));   // cvt_pkrtz native type

__device__ __forceinline__ float dot2(unsigned int a, unsigned int b, float c) {
    return __builtin_amdgcn_fdot2(__builtin_bit_cast(h2, a),
                                  __builtin_bit_cast(h2, b), c, false);
}

// ---------------------------------------------------------------------------
// Pass A: pointwise double-EMA scan (~33 us, ~6.1 TB/s). Block 0 also packs
// conv weights into DUAL f16 pair sets per ky row (10 u32 each):
//   E = (w0,w1)(w2,w3)(w4,w5)(w6,w7)(w8,0)   -> even-offset outputs
//   O = (0,w0)(w1,w2)(w3,w4)(w5,w6)(w7,w8)   -> odd-offset outputs
// so conv needs NO per-row alignbit shifts at all.
// ---------------------------------------------------------------------------
__global__ __launch_bounds__(256) void scan_chunk(
    const float* __restrict__ x, unsigned int* __restrict__ Rbuf,
    float* __restrict__ state, const float* __restrict__ wp,
    unsigned int* __restrict__ wq, int t0, int tc)
{
    if (t0 == 0 && blockIdx.x == 0 && threadIdx.x < 9) {
        int ky = threadIdx.x;
        unsigned int hh[9];
        #pragma unroll
        for (int kx = 0; kx < 9; ++kx) {
            _Float16 hv = (_Float16)wp[ky * 9 + kx];
            hh[kx] = (unsigned int)__builtin_bit_cast(unsigned short, hv);
        }
        unsigned int* wr = wq + ky * 10;
        wr[0] = hh[0] | (hh[1] << 16);   // E0
        wr[1] = hh[2] | (hh[3] << 16);   // E1
        wr[2] = hh[4] | (hh[5] << 16);   // E2
        wr[3] = hh[6] | (hh[7] << 16);   // E3
        wr[4] = hh[8];                   // E4 = (w8, 0)
        wr[5] = hh[0] << 16;             // O0 = (0, w0)
        wr[6] = hh[1] | (hh[2] << 16);   // O1
        wr[7] = hh[3] | (hh[4] << 16);   // O2
        wr[8] = hh[5] | (hh[6] << 16);   // O3
        wr[9] = hh[7] | (hh[8] << 16);   // O4
    }

    const int gid = blockIdx.x * 256 + threadIdx.x;      // 0 .. HW/4-1
    const v4f* xp = (const v4f*)x + (size_t)t0 * (HW / 4) + gid;
    v2u* rp = (v2u*)Rbuf + gid;
    v4f* st = (v4f*)state;

    v4f p, r;
    if (t0 == 0) {
        p = (v4f)0.f; r = (v4f)0.f;
    } else {
        p = st[gid];
        r = st[HW / 4 + gid];
    }

#define SCAN_STEP(xv)                                                        \
    {                                                                        \
        hr2 h0 = __builtin_amdgcn_cvt_pkrtz(r.x, r.y);                       \
        hr2 h1 = __builtin_amdgcn_cvt_pkrtz(r.z, r.w);                       \
        v2u pk;                                                              \
        pk.x = __builtin_bit_cast(unsigned int, h0);                         \
        pk.y = __builtin_bit_cast(unsigned int, h1);                         \
        rp[(size_t)t * (HW / 4)] = pk;                                       \
        v4f rn = DECAY * r + p;                                              \
        p = DECAY * p + (xv);                                                \
        r = rn;                                                              \
        ++t;                                                                 \
    }

    int t = 0;
    const int t4 = tc & ~3;
    for (; t < t4;) {
        v4f x0 = __builtin_nontemporal_load(&xp[(size_t)(t + 0) * (HW / 4)]);
        v4f x1 = __builtin_nontemporal_load(&xp[(size_t)(t + 1) * (HW / 4)]);
        v4f x2 = __builtin_nontemporal_load(&xp[(size_t)(t + 2) * (HW / 4)]);
        v4f x3 = __builtin_nontemporal_load(&xp[(size_t)(t + 3) * (HW / 4)]);
        SCAN_STEP(x0); SCAN_STEP(x1); SCAN_STEP(x2); SCAN_STEP(x3);
    }
    for (; t < tc;) {
        v4f xv = __builtin_nontemporal_load(&xp[(size_t)t * (HW / 4)]);
        SCAN_STEP(xv);
    }
#undef SCAN_STEP

    st[gid] = p;
    st[HW / 4 + gid] = r;
}

// ---------------------------------------------------------------------------
// Pass B: 9x9 conv, f16 in / fp32 out, v_dot2_f32_f16, ZP=4 planes per block
// (2048 blocks -> ~6 LDS-capped blocks/CU, ~20 waves/CU), two-plane-deep
// register prefetch, double-buffered LDS, one barrier per plane. Wave = one
// region row per ds_read: conflict-free. Dual weight pairs: zero alignbits.
// ---------------------------------------------------------------------------
#define BX 256
#define BY 16
#define ZP 4          // time planes per block
#define RGROWS 24     // 16 + 8 halo
#define RSTRE 272     // LDS row stride in f16 elems (544 B)
#define RCHUNK 66     // 4-elem (8 B) chunks per row (264 elems used)
#define NCHK 7        // ceil(24*66/256)

__global__ __launch_bounds__(256) void conv_chunk(
    const unsigned short* __restrict__ Rbuf, const unsigned int* __restrict__ wq,
    float* __restrict__ out, int t0, int tc)
{
    __shared__ unsigned short regA[RGROWS * RSTRE];   // 13,056 B
    __shared__ unsigned short regB[RGROWS * RSTRE];

    const int tid = threadIdx.x;
    const int tX = blockIdx.x, tY = blockIdx.y;
    const int z0 = blockIdx.z * ZP;
    const int zc = (tc - z0 < ZP) ? (tc - z0) : ZP;
    const int X0 = tX * BX - 4, Y0 = tY * BY - 4;
    const unsigned short* Rbase = Rbuf + (size_t)z0 * HW;

    unsigned int wk[90];               // uniform -> SGPRs / s_loads
    #pragma unroll
    for (int q = 0; q < 90; ++q) wk[q] = wq[q];

    // per-thread staging slots (static for whole kernel)
    int goffk[NCHK], laddrk[NCHK];
    unsigned smask = 0;
    #pragma unroll
    for (int k = 0; k < NCHK; ++k) {
        int e = tid + 256 * k;
        int rr = e / RCHUNK, c = e - rr * RCHUNK;
        int gy = Y0 + rr, gx = X0 + 4 * c;
        bool inr = (e < RGROWS * RCHUNK);
        bool inimg = inr && (unsigned)gy < H && (unsigned)gx < W;
        goffk[k] = gy * W + gx;
        laddrk[k] = rr * RSTRE + 4 * c;
        if (inr) smask |= (1u << k);
        if (inimg) smask |= (1u << (k + 16));
    }

#define LOADPLANE(pf, zz)                                                    \
    {                                                                        \
        const unsigned short* Rp_ = Rbase + (size_t)(zz) * HW;               \
        _Pragma("unroll")                                                    \
        for (int k = 0; k < NCHK; ++k)                                       \
            pf[k] = (smask >> (k + 16) & 1)                                  \
                        ? *(const uint2*)(Rp_ + goffk[k])                    \
                        : make_uint2(0u, 0u);                                \
    }

#define WRITEPLANE(buf, pf)                                                  \
    {                                                                        \
        _Pragma("unroll")                                                    \
        for (int k = 0; k < NCHK; ++k)                                       \
            if (smask >> k & 1)                                              \
                *(uint2*)(&buf[laddrk[k]]) = pf[k];                          \
    }

    const int i = tid & 63;     // col chunk: region elems 4i..4i+11 window
    const int j = tid >> 6;     // 0..3 -> output rows 4j..4j+3
    const int rbase = 4 * j;
    float* opb = out + (size_t)(t0 + z0) * HW
                     + (size_t)((tY * BY + 4 * j) * W) + (tX * BX + 4 * i);

#define COMPUTE(bufc, zz)                                                    \
    {                                                                        \
        float acc[4][4];                                                     \
        _Pragma("unroll")                                                    \
        for (int a = 0; a < 4; ++a)                                          \
            _Pragma("unroll")                                                \
            for (int b = 0; b < 4; ++b) acc[a][b] = 0.f;                     \
        _Pragma("unroll")                                                    \
        for (int r = 0; r < 12; ++r) {                                       \
            const unsigned short* rp = &bufc[(rbase + r) * RSTRE + 4 * i];   \
            uint2 va = *(const uint2*)(rp);                                  \
            uint2 vb = *(const uint2*)(rp + 4);                              \
            uint2 vc = *(const uint2*)(rp + 8);                              \
            unsigned int e0 = va.x, e1 = va.y, e2 = vb.x;                    \
            unsigned int e3 = vb.y, e4 = vc.x, e5 = vc.y;                    \
            _Pragma("unroll")                                                \
            for (int oy = 0; oy < 4; ++oy) {                                 \
                const int ky = r - oy;                                       \
                if (ky >= 0 && ky <= 8) {                                    \
                    const unsigned int* wc = &wk[ky * 10];                   \
                    acc[oy][0] = dot2(e0, wc[0], acc[oy][0]);                \
                    acc[oy][0] = dot2(e1, wc[1], acc[oy][0]);                \
                    acc[oy][0] = dot2(e2, wc[2], acc[oy][0]);                \
                    acc[oy][0] = dot2(e3, wc[3], acc[oy][0]);                \
                    acc[oy][0] = dot2(e4, wc[4], acc[oy][0]);                \
                    acc[oy][1] = dot2(e0, wc[5], acc[oy][1]);                \
                    acc[oy][1] = dot2(e1, wc[6], acc[oy][1]);                \
                    acc[oy][1] = dot2(e2, wc[7], acc[oy][1]);                \
                    acc[oy][1] = dot2(e3, wc[8], acc[oy][1]);                \
                    acc[oy][1] = dot2(e4, wc[9], acc[oy][1]);                \
                    acc[oy][2] = dot2(e1, wc[0], acc[oy][2]);                \
                    acc[oy][2] = dot2(e2, wc[1], acc[oy][2]);                \
                    acc[oy][2] = dot2(e3, wc[2], acc[oy][2]);                \
                    acc[oy][2] = dot2(e4, wc[3], acc[oy][2]);                \
                    acc[oy][2] = dot2(e5, wc[4], acc[oy][2]);                \
                    acc[oy][3] = dot2(e1, wc[5], acc[oy][3]);                \
                    acc[oy][3] = dot2(e2, wc[6], acc[oy][3]);                \
                    acc[oy][3] = dot2(e3, wc[7], acc[oy][3]);                \
                    acc[oy][3] = dot2(e4, wc[8], acc[oy][3]);                \
                    acc[oy][3] = dot2(e5, wc[9], acc[oy][3]);                \
                }                                                            \
            }                                                                \
        }                                                                    \
        float* op = opb + (size_t)(zz) * HW;                                 \
        _Pragma("unroll")                                                    \
        for (int oy = 0; oy < 4; ++oy) {                                     \
            v4f v = {acc[oy][0], acc[oy][1], acc[oy][2], acc[oy][3]};        \
            __builtin_nontemporal_store(v, (v4f*)(op + (size_t)oy * W));     \
        }                                                                    \
    }

    uint2 pfA[NCHK], pfB[NCHK];
    LOADPLANE(pfA, 0);
    if (zc > 1) LOADPLANE(pfB, 1);
    WRITEPLANE(regA, pfA);
    __syncthreads();

    for (int zz = 0; zz < zc; zz += 2) {
        // even plane: LDS regA holds zz; pfB holds zz+1 (in flight)
        if (zz + 2 < zc) LOADPLANE(pfA, zz + 2);   // issue 2 phases early
        COMPUTE(regA, zz);
        if (zz + 1 < zc) {
            WRITEPLANE(regB, pfB);                 // waits pfB (long cover)
            __syncthreads();
            // odd plane: LDS regB holds zz+1; pfA in flight for zz+2
            if (zz + 3 < zc) LOADPLANE(pfB, zz + 3);
            COMPUTE(regB, zz + 1);
            if (zz + 2 < zc) {
                WRITEPLANE(regA, pfA);
                __syncthreads();
            }
        }
    }
#undef COMPUTE
#undef LOADPLANE
#undef WRITEPLANE
}

// ---------------------------------------------------------------------------
extern "C" void kernel_launch(void* const* d_in, const int* in_sizes, int n_in,
                              void* d_out, int out_size, void* d_ws, size_t ws_size,
                              hipStream_t stream) {
    const float* x = (const float*)d_in[0];  // [128,1,512,512]
    const float* w = (const float*)d_in[1];  // [1,1,9,9]
    float* out = (float*)d_out;              // [128,1,512,512]

    unsigned int* wq = (unsigned int*)d_ws;                    // 128 u32 slot
    float* state = (float*)((char*)d_ws + 512);                // 2 fp32 planes
    unsigned short* Rbuf = (unsigned short*)(state + 2 * (size_t)HW);

    size_t head_b = 512 + 2 * (size_t)HW * sizeof(float);
    size_t plane_b = (size_t)HW * sizeof(unsigned short);
    int maxTc = 1;
    if (ws_size > head_b + plane_b)
        maxTc = (int)((ws_size - head_b) / plane_b);
    int Tc = T;
    if (Tc > maxTc) Tc = maxTc;
    if (Tc < 1) Tc = 1;

    for (int t0 = 0; t0 < T; t0 += Tc) {
        int tc = T - t0;
        if (tc > Tc) tc = Tc;
        scan_chunk<<<dim3(HW / 1024), 256, 0, stream>>>(
            x, (unsigned int*)Rbuf, state, w, wq, t0, tc);
        conv_chunk<<<dim3(W / BX, H / BY, (tc + ZP - 1) / ZP), 256, 0, stream>>>(
            Rbuf, wq, out, t0, tc);
    }
}

// Round 14
// 93.200 us; speedup vs baseline: 1.1473x; 1.0265x over previous
//
#include <hip/hip_runtime.h>

#define H 512
#define W 512
#define HW (H * W)
#define T 128
#define DECAY 0.8f

typedef float v4f __attribute__((ext_vector_type(4)));
typedef unsigned int v2u __attribute__((ext_vector_type(2)));
typedef _Float16 f16x8 __attribute__((ext_vector_type(8)));
typedef float f32x4 __attribute__((ext_vector_type(4)));
typedef __fp16 hr2 __attribute__((ext_vector_type(2)));   // cvt_pkrtz native type

// ---------------------------------------------------------------------------
// Pass A: pointwise double-EMA scan (~33 us, ~6.1 TB/s). R stored packed f16.
// Blocks 0..1 at t0==0 also build the conv B-matrix (224x16 f16) in MFMA
// fragment order: B[k=(ky,dc)][n] = w[ky][dc-n] (0 if out of band), laid out
// so conv lane l, mfma q loads Bp[q*64+l] as one uint4 (8 f16).
// ---------------------------------------------------------------------------
__global__ __launch_bounds__(256) void scan_chunk(
    const float* __restrict__ x, unsigned int* __restrict__ Rbuf,
    float* __restrict__ state, const float* __restrict__ wp,
    uint4* __restrict__ Bp, int t0, int tc)
{
    if (t0 == 0 && blockIdx.x < 2) {
        int idx = blockIdx.x * 256 + threadIdx.x;   // 0..511
        if (idx < 448) {
            int q = idx >> 6, l = idx & 63;
            int n = l & 15, g = l >> 4;
            unsigned int vs[8];
            #pragma unroll
            for (int j = 0; j < 8; ++j) {
                int k = 32 * q + 8 * g + j;
                int ky = k / 24, dc = k - ky * 24;
                int kx = dc - n;
                float wv = (ky < 9 && kx >= 0 && kx <= 8) ? wp[ky * 9 + kx] : 0.f;
                _Float16 hv = (_Float16)wv;
                vs[j] = (unsigned int)__builtin_bit_cast(unsigned short, hv);
            }
            uint4 pk;
            pk.x = vs[0] | (vs[1] << 16);
            pk.y = vs[2] | (vs[3] << 16);
            pk.z = vs[4] | (vs[5] << 16);
            pk.w = vs[6] | (vs[7] << 16);
            Bp[idx] = pk;
        }
    }

    const int gid = blockIdx.x * 256 + threadIdx.x;      // 0 .. HW/4-1
    const v4f* xp = (const v4f*)x + (size_t)t0 * (HW / 4) + gid;
    v2u* rp = (v2u*)Rbuf + gid;
    v4f* st = (v4f*)state;

    v4f p, r;
    if (t0 == 0) {
        p = (v4f)0.f; r = (v4f)0.f;
    } else {
        p = st[gid];
        r = st[HW / 4 + gid];
    }

#define SCAN_STEP(xv)                                                        \
    {                                                                        \
        hr2 h0 = __builtin_amdgcn_cvt_pkrtz(r.x, r.y);                       \
        hr2 h1 = __builtin_amdgcn_cvt_pkrtz(r.z, r.w);                       \
        v2u pk;                                                              \
        pk.x = __builtin_bit_cast(unsigned int, h0);                         \
        pk.y = __builtin_bit_cast(unsigned int, h1);                         \
        rp[(size_t)t * (HW / 4)] = pk;                                       \
        v4f rn = DECAY * r + p;                                              \
        p = DECAY * p + (xv);                                                \
        r = rn;                                                              \
        ++t;                                                                 \
    }

    int t = 0;
    const int t4 = tc & ~3;
    for (; t < t4;) {
        v4f x0 = __builtin_nontemporal_load(&xp[(size_t)(t + 0) * (HW / 4)]);
        v4f x1 = __builtin_nontemporal_load(&xp[(size_t)(t + 1) * (HW / 4)]);
        v4f x2 = __builtin_nontemporal_load(&xp[(size_t)(t + 2) * (HW / 4)]);
        v4f x3 = __builtin_nontemporal_load(&xp[(size_t)(t + 3) * (HW / 4)]);
        SCAN_STEP(x0); SCAN_STEP(x1); SCAN_STEP(x2); SCAN_STEP(x3);
    }
    for (; t < tc;) {
        v4f xv = __builtin_nontemporal_load(&xp[(size_t)t * (HW / 4)]);
        SCAN_STEP(xv);
    }
#undef SCAN_STEP

    st[gid] = p;
    st[HW / 4 + gid] = r;
}

// ---------------------------------------------------------------------------
// Pass B: 9x9 conv as implicit GEMM on the matrix cores.
// Per wave: one 16x16 output tile per plane. D[m][n] = out[y0+m][x0w+n] =
// sum_k A[m][k] B[k][n], k=(ky,dc) in [0,216)->pad 224, A[m][k] =
// subregion[m+ky][dc] (f16, private 25x56 LDS region per wave, stride 112B),
// B = constant banded weight matrix from Bp. 7x mfma_f32_16x16x32_f16 +
// 7x ds_read_b128 per tile. No barriers (waves fully independent); dbuf LDS
// + one-deep register prefetch covers HBM latency. ZP=8 planes per block.
// ---------------------------------------------------------------------------
#define ZP 8
#define SUBROWS 25
#define SUBSTR 56                   // f16 elems per sub-region row (112 B)
#define SUBE (SUBROWS * SUBSTR)     // 1400 elems
#define BUFE (4 * SUBE)             // 5600 elems per buffer (4 waves)

__global__ __launch_bounds__(256) void conv_mfma(
    const unsigned short* __restrict__ Rbuf, const uint4* __restrict__ Bp,
    float* __restrict__ out, int t0, int tc)
{
    __shared__ __align__(16) unsigned short lds[2 * BUFE];   // 22,400 B

    const int tid = threadIdx.x;
    const int l = tid & 63, wvi = tid >> 6;
    const int bx = blockIdx.x, by = blockIdx.y;
    const int z0 = blockIdx.z * ZP;
    const int zc = (tc - z0 < ZP) ? (tc - z0) : ZP;
    const int x0w = bx * 64 + wvi * 16;   // wave's output col base
    const int y0 = by * 16;
    const unsigned short* Rbase = Rbuf + (size_t)z0 * HW;

    // B fragments (28 VGPRs), constant per kernel
    f16x8 bf[7];
    #pragma unroll
    for (int q = 0; q < 7; ++q)
        bf[q] = __builtin_bit_cast(f16x8, Bp[q * 64 + l]);

    // A-read elem offsets per mfma q: (ky)*SUBSTR + dc0 for k0 = 32q + 8g
    const int g = l >> 4, m = l & 15;
    int aoff[7];
    #pragma unroll
    for (int q = 0; q < 7; ++q) {
        int k0 = 32 * q + 8 * g;
        int ky = k0 / 24, dc0 = k0 - ky * 24;
        aoff[q] = wvi * SUBE + ky * SUBSTR + dc0;
    }
    const int abase = m * SUBSTR;

    // staging slots: 24 rows x 6 chunks of 4 f16 = 144 slots per sub-region
    int goffs[3], laddr[3];
    unsigned vmask = 0;
    #pragma unroll
    for (int kk = 0; kk < 3; ++kk) {
        int s = l + 64 * kk;
        int row = s / 6, c = s - row * 6;
        int gy = y0 - 4 + row, gx = x0w - 4 + 4 * c;
        bool inr = (s < 144);
        bool ok = inr && (unsigned)gy < H && (unsigned)gx < W;
        goffs[kk] = gy * W + gx;
        laddr[kk] = wvi * SUBE + row * SUBSTR + 4 * c;
        if (ok) vmask |= (1u << kk);
        if (inr) vmask |= (1u << (kk + 8));
    }

    // zero pad row 24 of this wave's sub-region in BOTH buffers (NaN guard
    // for the k>=216 zero-weight taps that read it)
    if (l < 14) {
        uint2 z2 = make_uint2(0u, 0u);
        *(uint2*)(lds + wvi * SUBE + 24 * SUBSTR + 4 * l) = z2;
        *(uint2*)(lds + BUFE + wvi * SUBE + 24 * SUBSTR + 4 * l) = z2;
    }

#define LOADPLANE(pf, zz)                                                    \
    {                                                                        \
        const unsigned short* Rp_ = Rbase + (size_t)(zz) * HW;               \
        _Pragma("unroll")                                                    \
        for (int kk = 0; kk < 3; ++kk)                                       \
            pf[kk] = (vmask >> kk & 1) ? *(const uint2*)(Rp_ + goffs[kk])    \
                                       : make_uint2(0u, 0u);                 \
    }

#define WRITEPLANE(boff, pf)                                                 \
    {                                                                        \
        _Pragma("unroll")                                                    \
        for (int kk = 0; kk < 3; ++kk)                                       \
            if (vmask >> (kk + 8) & 1)                                       \
                *(uint2*)(lds + (boff) + laddr[kk]) = pf[kk];                \
    }

    uint2 pf[3];
    LOADPLANE(pf, 0);
    WRITEPLANE(0, pf);

    for (int zz = 0; zz < zc; ++zz) {
        const int cur = (zz & 1) * BUFE;
        const int nxt = BUFE - cur;
        if (zz + 1 < zc) LOADPLANE(pf, zz + 1);   // issue before compute

        f32x4 acc = {0.f, 0.f, 0.f, 0.f};
        #pragma unroll
        for (int q = 0; q < 7; ++q) {
            f16x8 af = *(const f16x8*)(lds + cur + abase + aoff[q]);
            acc = __builtin_amdgcn_mfma_f32_16x16x32_f16(af, bf[q], acc, 0, 0, 0);
        }

        float* op = out + (size_t)(t0 + z0 + zz) * HW
                        + (size_t)(y0 + g * 4) * W + x0w + m;
        #pragma unroll
        for (int i = 0; i < 4; ++i)
            __builtin_nontemporal_store(acc[i], op + (size_t)i * W);

        if (zz + 1 < zc) WRITEPLANE(nxt, pf);     // waits pf after compute
    }
#undef LOADPLANE
#undef WRITEPLANE
}

// ---------------------------------------------------------------------------
extern "C" void kernel_launch(void* const* d_in, const int* in_sizes, int n_in,
                              void* d_out, int out_size, void* d_ws, size_t ws_size,
                              hipStream_t stream) {
    const float* x = (const float*)d_in[0];  // [128,1,512,512]
    const float* w = (const float*)d_in[1];  // [1,1,9,9]
    float* out = (float*)d_out;              // [128,1,512,512]

    uint4* Bp = (uint4*)d_ws;                                  // 7168 B used
    float* state = (float*)((char*)d_ws + 8192);               // 2 fp32 planes
    unsigned short* Rbuf = (unsigned short*)(state + 2 * (size_t)HW);

    size_t head_b = 8192 + 2 * (size_t)HW * sizeof(float);
    size_t plane_b = (size_t)HW * sizeof(unsigned short);
    int maxTc = 1;
    if (ws_size > head_b + plane_b)
        maxTc = (int)((ws_size - head_b) / plane_b);
    int Tc = T;
    if (Tc > maxTc) Tc = maxTc;
    if (Tc < 1) Tc = 1;

    for (int t0 = 0; t0 < T; t0 += Tc) {
        int tc = T - t0;
        if (tc > Tc) tc = Tc;
        scan_chunk<<<dim3(HW / 1024), 256, 0, stream>>>(
            x, (unsigned int*)Rbuf, state, w, Bp, t0, tc);
        conv_mfma<<<dim3(W / 64, H / 16, (tc + ZP - 1) / ZP), 256, 0, stream>>>(
            Rbuf, Bp, out, t0, tc);
    }
}

// Round 15
// 89.947 us; speedup vs baseline: 1.1888x; 1.0362x over previous
//
#include <hip/hip_runtime.h>

#define H 512
#define W 512
#define HW (H * W)
#define T 128
#define DECAY 0.8f

typedef float v4f __attribute__((ext_vector_type(4)));
typedef unsigned int v2u __attribute__((ext_vector_type(2)));
typedef _Float16 f16x8 __attribute__((ext_vector_type(8)));
typedef float f32x4 __attribute__((ext_vector_type(4)));
typedef __fp16 hr2 __attribute__((ext_vector_type(2)));   // cvt_pkrtz native type

// ---------------------------------------------------------------------------
// Pass A: pointwise double-EMA scan (~33 us). R stored packed f16. Blocks 0..1
// at t0==0 also build the conv B-matrix (224x16 f16) in MFMA fragment order:
// B[k=(ky,dc)][n] = w[ky][dc-n], lane l mfma q reads Bp[q*64+l] (8 f16).
// ---------------------------------------------------------------------------
__global__ __launch_bounds__(256) void scan_chunk(
    const float* __restrict__ x, unsigned int* __restrict__ Rbuf,
    float* __restrict__ state, const float* __restrict__ wp,
    uint4* __restrict__ Bp, int t0, int tc)
{
    if (t0 == 0 && blockIdx.x < 2) {
        int idx = blockIdx.x * 256 + threadIdx.x;   // 0..511
        if (idx < 448) {
            int q = idx >> 6, l = idx & 63;
            int n = l & 15, g = l >> 4;
            unsigned int vs[8];
            #pragma unroll
            for (int j = 0; j < 8; ++j) {
                int k = 32 * q + 8 * g + j;
                int ky = k / 24, dc = k - ky * 24;
                int kx = dc - n;
                float wv = (ky < 9 && kx >= 0 && kx <= 8) ? wp[ky * 9 + kx] : 0.f;
                _Float16 hv = (_Float16)wv;
                vs[j] = (unsigned int)__builtin_bit_cast(unsigned short, hv);
            }
            uint4 pk;
            pk.x = vs[0] | (vs[1] << 16);
            pk.y = vs[2] | (vs[3] << 16);
            pk.z = vs[4] | (vs[5] << 16);
            pk.w = vs[6] | (vs[7] << 16);
            Bp[idx] = pk;
        }
    }

    const int gid = blockIdx.x * 256 + threadIdx.x;      // 0 .. HW/4-1
    const v4f* xp = (const v4f*)x + (size_t)t0 * (HW / 4) + gid;
    v2u* rp = (v2u*)Rbuf + gid;
    v4f* st = (v4f*)state;

    v4f p, r;
    if (t0 == 0) {
        p = (v4f)0.f; r = (v4f)0.f;
    } else {
        p = st[gid];
        r = st[HW / 4 + gid];
    }

#define SCAN_STEP(xv)                                                        \
    {                                                                        \
        hr2 h0 = __builtin_amdgcn_cvt_pkrtz(r.x, r.y);                       \
        hr2 h1 = __builtin_amdgcn_cvt_pkrtz(r.z, r.w);                       \
        v2u pk;                                                              \
        pk.x = __builtin_bit_cast(unsigned int, h0);                         \
        pk.y = __builtin_bit_cast(unsigned int, h1);                         \
        rp[(size_t)t * (HW / 4)] = pk;                                       \
        v4f rn = DECAY * r + p;                                              \
        p = DECAY * p + (xv);                                                \
        r = rn;                                                              \
        ++t;                                                                 \
    }

    int t = 0;
    const int t4 = tc & ~3;
    for (; t < t4;) {
        v4f x0 = __builtin_nontemporal_load(&xp[(size_t)(t + 0) * (HW / 4)]);
        v4f x1 = __builtin_nontemporal_load(&xp[(size_t)(t + 1) * (HW / 4)]);
        v4f x2 = __builtin_nontemporal_load(&xp[(size_t)(t + 2) * (HW / 4)]);
        v4f x3 = __builtin_nontemporal_load(&xp[(size_t)(t + 3) * (HW / 4)]);
        SCAN_STEP(x0); SCAN_STEP(x1); SCAN_STEP(x2); SCAN_STEP(x3);
    }
    for (; t < tc;) {
        v4f xv = __builtin_nontemporal_load(&xp[(size_t)t * (HW / 4)]);
        SCAN_STEP(xv);
    }
#undef SCAN_STEP

    st[gid] = p;
    st[HW / 4 + gid] = r;
}

// ---------------------------------------------------------------------------
// Pass B: 9x9 conv as implicit GEMM, block-cooperative COALESCED staging.
// Block = 256w x 16h tile, shared region 24 rows x 264 f16 (+pad row 24).
// LDS row = 40 x 16B slots (stride 640 B, multiple of 32 banks) with XOR
// swizzle slot ^= (row&7) on BOTH staging writes and A-reads -> uniform
// 8-lanes-per-bank-group (contiguous-b128 throughput). Wave wvi computes 4
// 16x16 tiles: per tile 7 ds_read_b128 + 7 mfma_f32_16x16x32_f16, K=(ky,dc)
// padded 216->224 (pad row zeroed once). Dbuf LDS + 2-deep register
// prefetch + 1 barrier/plane (round-13 pipeline), ZP=4 planes per block.
// ---------------------------------------------------------------------------
#define ZP 4
#define RGROWS 24
#define RCHUNK 66     // 8B chunks per region row (264 elems)
#define NCHK 7        // ceil(24*66/256)
#define ROWB 640      // LDS bytes per row (40 slots)
#define BUFB (25 * ROWB)

__global__ __launch_bounds__(256) void conv_mfma(
    const unsigned short* __restrict__ Rbuf, const uint4* __restrict__ Bp,
    float* __restrict__ out, int t0, int tc)
{
    __shared__ __align__(16) char lds[2 * BUFB];   // 32,000 B

    const int tid = threadIdx.x;
    const int l = tid & 63, wvi = tid >> 6;
    const int bx = blockIdx.x, by = blockIdx.y;
    const int z0 = blockIdx.z * ZP;
    const int zc = (tc - z0 < ZP) ? (tc - z0) : ZP;
    const int X0 = bx * 256 - 4, Y0 = by * 16 - 4;
    const unsigned short* Rbase = Rbuf + (size_t)z0 * HW;

    // B fragments (constant per kernel)
    f16x8 bf[7];
    #pragma unroll
    for (int q = 0; q < 7; ++q)
        bf[q] = __builtin_bit_cast(f16x8, Bp[q * 64 + l]);

    // A-read lane constants per mfma q: k0 = 32q+8g -> (ky, dc0)
    const int g = l >> 4, m = l & 15;
    int aoffb[7], ark[7], adq[7];
    #pragma unroll
    for (int q = 0; q < 7; ++q) {
        int k0 = 32 * q + 8 * g;
        int ky = k0 / 24, dc0 = k0 - 24 * ky;
        aoffb[q] = (m + ky) * ROWB;
        ark[q] = (m + ky) & 7;
        adq[q] = dc0 >> 3;          // 0,1,2
    }

    // staging slots (coalesced: consecutive lanes -> consecutive 8B chunks)
    int goffk[NCHK], laddrk[NCHK];
    unsigned smask = 0;
    #pragma unroll
    for (int k = 0; k < NCHK; ++k) {
        int e = tid + 256 * k;
        int row = e / RCHUNK, c = e - row * RCHUNK;
        int gy = Y0 + row, gx = X0 + 4 * c;
        bool inr = (e < RGROWS * RCHUNK);
        bool inimg = inr && (unsigned)gy < H && (unsigned)gx < W;
        goffk[k] = gy * W + gx;
        laddrk[k] = row * ROWB + ((((c >> 1) ^ (row & 7))) << 4) + 8 * (c & 1);
        if (inr) smask |= (1u << k);
        if (inimg) smask |= (1u << (k + 16));
    }

    // zero pad row 24 (K>=216 zero-weight taps read it) in both buffers
    if (tid < 80) {
        int b = tid / 40, s = tid - 40 * (tid / 40);
        uint4 z4 = make_uint4(0u, 0u, 0u, 0u);
        *(uint4*)(lds + b * BUFB + 24 * ROWB + 16 * s) = z4;
    }

#define LOADPLANE(pf, zz)                                                    \
    {                                                                        \
        const unsigned short* Rp_ = Rbase + (size_t)(zz) * HW;               \
        _Pragma("unroll")                                                    \
        for (int k = 0; k < NCHK; ++k)                                       \
            pf[k] = (smask >> (k + 16) & 1)                                  \
                        ? *(const uint2*)(Rp_ + goffk[k])                    \
                        : make_uint2(0u, 0u);                                \
    }

#define WRITEPLANE(boff, pf)                                                 \
    {                                                                        \
        _Pragma("unroll")                                                    \
        for (int k = 0; k < NCHK; ++k)                                       \
            if (smask >> k & 1)                                              \
                *(uint2*)(lds + (boff) + laddrk[k]) = pf[k];                 \
    }

    float* opb = out + (size_t)(t0 + z0) * HW
                     + (size_t)(by * 16 + 4 * g) * W + bx * 256 + 64 * wvi + m;

#define COMPUTE(boff, zz)                                                    \
    {                                                                        \
        const char* buf = lds + (boff);                                      \
        _Pragma("unroll")                                                    \
        for (int n = 0; n < 4; ++n) {                                        \
            f32x4 acc = {0.f, 0.f, 0.f, 0.f};                                \
            _Pragma("unroll")                                                \
            for (int q = 0; q < 7; ++q) {                                    \
                int cso = (((8 * wvi + 2 * n + adq[q]) ^ ark[q]) << 4);      \
                f16x8 af = *(const f16x8*)(buf + aoffb[q] + cso);            \
                acc = __builtin_amdgcn_mfma_f32_16x16x32_f16(                \
                    af, bf[q], acc, 0, 0, 0);                                \
            }                                                                \
            float* op = opb + (size_t)(zz) * HW + 16 * n;                    \
            _Pragma("unroll")                                                \
            for (int i = 0; i < 4; ++i)                                      \
                __builtin_nontemporal_store(acc[i], op + (size_t)i * W);     \
        }                                                                    \
    }

    uint2 pfA[NCHK], pfB[NCHK];
    LOADPLANE(pfA, 0);
    if (zc > 1) LOADPLANE(pfB, 1);
    WRITEPLANE(0, pfA);
    __syncthreads();

    for (int zz = 0; zz < zc; zz += 2) {
        if (zz + 2 < zc) LOADPLANE(pfA, zz + 2);   // issue 2 phases early
        COMPUTE(0, zz);
        if (zz + 1 < zc) {
            WRITEPLANE(BUFB, pfB);                 // waits pfB (long cover)
            __syncthreads();
            if (zz + 3 < zc) LOADPLANE(pfB, zz + 3);
            COMPUTE(BUFB, zz + 1);
            if (zz + 2 < zc) {
                WRITEPLANE(0, pfA);
                __syncthreads();
            }
        }
    }
#undef COMPUTE
#undef LOADPLANE
#undef WRITEPLANE
}

// ---------------------------------------------------------------------------
extern "C" void kernel_launch(void* const* d_in, const int* in_sizes, int n_in,
                              void* d_out, int out_size, void* d_ws, size_t ws_size,
                              hipStream_t stream) {
    const float* x = (const float*)d_in[0];  // [128,1,512,512]
    const float* w = (const float*)d_in[1];  // [1,1,9,9]
    float* out = (float*)d_out;              // [128,1,512,512]

    uint4* Bp = (uint4*)d_ws;                                  // 7168 B used
    float* state = (float*)((char*)d_ws + 8192);               // 2 fp32 planes
    unsigned short* Rbuf = (unsigned short*)(state + 2 * (size_t)HW);

    size_t head_b = 8192 + 2 * (size_t)HW * sizeof(float);
    size_t plane_b = (size_t)HW * sizeof(unsigned short);
    int maxTc = 1;
    if (ws_size > head_b + plane_b)
        maxTc = (int)((ws_size - head_b) / plane_b);
    int Tc = T;
    if (Tc > maxTc) Tc = maxTc;
    if (Tc < 1) Tc = 1;

    for (int t0 = 0; t0 < T; t0 += Tc) {
        int tc = T - t0;
        if (tc > Tc) tc = Tc;
        scan_chunk<<<dim3(HW / 1024), 256, 0, stream>>>(
            x, (unsigned int*)Rbuf, state, w, Bp, t0, tc);
        conv_mfma<<<dim3(W / 256, H / 16, (tc + ZP - 1) / ZP), 256, 0, stream>>>(
            Rbuf, Bp, out, t0, tc);
    }
}